// Round 6
// baseline (1554.119 us; speedup 1.0000x reference)
//
#include <hip/hip_runtime.h>

// Residual VQ, bit-exact vs numpy. B=16 S=2048 D=64 K=8 M=2048.
//
// Numerics contract (verified bit-exact R1-R5, absmax 0.0):
//  - r2/c2: numpy pairwise_sum 8-accumulator order, no FMA contraction
//  - cross: numpy einsum SSE order: 4 chains (d mod 4), per 16-block groups
//           {12,8,4,0}+j, blocks ascending, hsum (L0+L1)+(L2+L3)
//  - t = fl(r2 - 2*cross) via fma(-2,cross,r2); d2 = fl(t + c2)
//  - argmin: first occurrence (strict <; combine ascending-m)
//
// R6: two-phase filter. Pass 1 (asm, hot): fma-chain approximate d2 (1 inst
// per element instead of mul+add; packed fp32 is half-rate on gfx950 so pk
// gained nothing) + running min + candidate BITMASK with margin 2e-4
// (rigorous bound on |d2a-d2exact| is ~2e-5: gamma_63*Sum|r c| ~1.3e-7 plus
// <=2 ulp(64) shared-quantization divergence; running-best filter is a
// superset of final-best filter, so the true argmin bit is always set).
// Pass 2 (C++, cold): exact SSE-order recompute for candidates, ascending m,
// strict < => first-occurrence preserved. VGPR_Count CSV is in granules of 2
// (R5 "48" = 96 actual) — the residual was register-resident all along.

#define BB 16
#define SS 2048
#define DD 64
#define KK 8
#define MM 2048
#define NPTS (BB * SS)      // 32768
#define QSIZE (NPTS * DD)   // 2097152
#define WPB 8               // waves per block
#define MCHUNK (MM / WPB)   // 256 m per wave

// ---- prep: c2[k][m] (numpy pairwise) ----
__global__ __launch_bounds__(256) void rvq_prep(const float* __restrict__ cb,
                                                float* __restrict__ c2) {
#pragma clang fp contract(off)
    int tid = blockIdx.x * 256 + threadIdx.x;  // 0 .. K*M-1
    const float* row = cb + (size_t)tid * DD;
    float r[8];
#pragma unroll
    for (int j = 0; j < 8; ++j) { float v = row[j]; r[j] = v * v; }
#pragma unroll
    for (int i = 8; i < DD; i += 8) {
#pragma unroll
        for (int j = 0; j < 8; ++j) { float v = row[i + j]; float t = v * v; r[j] += t; }
    }
    c2[tid] = ((r[0] + r[1]) + (r[2] + r[3])) + ((r[4] + r[5]) + (r[6] + r[7]));
}

// r2 group: 8 squares (mul then add, separate roundings) into accs v80..v87
#define R2G(a0,a1,a2,a3,a4,a5,a6,a7) \
    "v_mul_f32 v96, v" a0 ", v" a0 "\n\tv_add_f32 v80, v80, v96\n\t" \
    "v_mul_f32 v96, v" a1 ", v" a1 "\n\tv_add_f32 v81, v81, v96\n\t" \
    "v_mul_f32 v96, v" a2 ", v" a2 "\n\tv_add_f32 v82, v82, v96\n\t" \
    "v_mul_f32 v96, v" a3 ", v" a3 "\n\tv_add_f32 v83, v83, v96\n\t" \
    "v_mul_f32 v96, v" a4 ", v" a4 "\n\tv_add_f32 v84, v84, v96\n\t" \
    "v_mul_f32 v96, v" a5 ", v" a5 "\n\tv_add_f32 v85, v85, v96\n\t" \
    "v_mul_f32 v96, v" a6 ", v" a6 "\n\tv_add_f32 v86, v86, v96\n\t" \
    "v_mul_f32 v96, v" a7 ", v" a7 "\n\tv_add_f32 v87, v87, v96\n\t"

// fma quad: 4 interleaved chains v81..v84, d ascending (pass-1 order is free)
#define FQ(s0,s1,s2,s3,w0,w1,w2,w3) \
    "v_fma_f32 v81, s" s0 ", v" w0 ", v81\n\t" \
    "v_fma_f32 v82, s" s1 ", v" w1 ", v82\n\t" \
    "v_fma_f32 v83, s" s2 ", v" w2 ", v83\n\t" \
    "v_fma_f32 v84, s" s3 ", v" w3 ", v84\n\t"

// ---- one RVQ step ----
// grid = NPTS/64 = 512 blocks x 512 threads (8 waves).
// lane = point; wave = 256-m chunk.
__global__ __launch_bounds__(512, 4) void rvq_step(const float* __restrict__ res_in,
                                                   float* __restrict__ res_out,
                                                   const float* __restrict__ cbk,  // (M,D)
                                                   const float* __restrict__ c2k,  // (M,)
                                                   float* __restrict__ idx_out) {  // (NPTS,)
#pragma clang fp contract(off)
    const int tid = threadIdx.x;
    const int lane = tid & 63;
    const int wv = __builtin_amdgcn_readfirstlane(tid >> 6);  // wave-uniform
    const int point = blockIdx.x * 64 + lane;
    const int m0 = wv * MCHUNK;
    const float* cbw = cbk + (size_t)m0 * DD;
    const float* c2w = c2k + m0;
    const unsigned long long ra = (unsigned long long)(res_in + (size_t)point * DD);

    unsigned mk0, mk1, mk2, mk3, mk4, mk5, mk6, mk7;
    asm volatile(
        // ---- residual: 64 floats -> v[16:79] ----
        "global_load_dwordx4 v[16:19], %[ra], off\n\t"
        "global_load_dwordx4 v[20:23], %[ra], off offset:16\n\t"
        "global_load_dwordx4 v[24:27], %[ra], off offset:32\n\t"
        "global_load_dwordx4 v[28:31], %[ra], off offset:48\n\t"
        "global_load_dwordx4 v[32:35], %[ra], off offset:64\n\t"
        "global_load_dwordx4 v[36:39], %[ra], off offset:80\n\t"
        "global_load_dwordx4 v[40:43], %[ra], off offset:96\n\t"
        "global_load_dwordx4 v[44:47], %[ra], off offset:112\n\t"
        "global_load_dwordx4 v[48:51], %[ra], off offset:128\n\t"
        "global_load_dwordx4 v[52:55], %[ra], off offset:144\n\t"
        "global_load_dwordx4 v[56:59], %[ra], off offset:160\n\t"
        "global_load_dwordx4 v[60:63], %[ra], off offset:176\n\t"
        "global_load_dwordx4 v[64:67], %[ra], off offset:192\n\t"
        "global_load_dwordx4 v[68:71], %[ra], off offset:208\n\t"
        "global_load_dwordx4 v[72:75], %[ra], off offset:224\n\t"
        "global_load_dwordx4 v[76:79], %[ra], off offset:240\n\t"
        "s_waitcnt vmcnt(0)\n\t"
        // ---- r2, numpy pairwise 8-acc order (accs v80..v87) ----
        "v_mul_f32 v80, v16, v16\n\t"
        "v_mul_f32 v81, v17, v17\n\t"
        "v_mul_f32 v82, v18, v18\n\t"
        "v_mul_f32 v83, v19, v19\n\t"
        "v_mul_f32 v84, v20, v20\n\t"
        "v_mul_f32 v85, v21, v21\n\t"
        "v_mul_f32 v86, v22, v22\n\t"
        "v_mul_f32 v87, v23, v23\n\t"
        R2G("24","25","26","27","28","29","30","31")
        R2G("32","33","34","35","36","37","38","39")
        R2G("40","41","42","43","44","45","46","47")
        R2G("48","49","50","51","52","53","54","55")
        R2G("56","57","58","59","60","61","62","63")
        R2G("64","65","66","67","68","69","70","71")
        R2G("72","73","74","75","76","77","78","79")
        "v_add_f32 v96, v80, v81\n\t"
        "v_add_f32 v97, v82, v83\n\t"
        "v_add_f32 v96, v96, v97\n\t"
        "v_add_f32 v97, v84, v85\n\t"
        "v_add_f32 v80, v86, v87\n\t"
        "v_add_f32 v97, v97, v80\n\t"
        "v_add_f32 v80, v96, v97\n\t"      // r2 -> v80
        // ---- init: bestA v85, bit v86, cur-mask v87, stores v88-95 ----
        "v_mov_b32 v85, 0x7f800000\n\t"
        "v_mov_b32 v86, 1\n\t"
        "v_mov_b32 v87, 0\n\t"
        "v_mov_b32 v88, 0\n\t"
        "v_mov_b32 v89, 0\n\t"
        "v_mov_b32 v90, 0\n\t"
        "v_mov_b32 v91, 0\n\t"
        "v_mov_b32 v92, 0\n\t"
        "v_mov_b32 v93, 0\n\t"
        "v_mov_b32 v94, 0\n\t"
        "v_mov_b32 v95, 0\n\t"
        "s_mov_b32 s29, 0\n\t"             // byte offset into chunk
        "s_mov_b32 s25, 8\n\t"             // outer (sub-blocks of 32 m)
        "Lout_%=:\n\t"
        "s_mov_b32 s24, 32\n\t"            // inner
        "Linn_%=:\n\t"
        // ---- row m -> s[32:95]; c2m -> s28 ----
        "s_load_dwordx16 s[32:47], %[cb], s29\n\t"
        "s_add_u32 s30, s29, 64\n\t"
        "s_load_dwordx16 s[48:63], %[cb], s30\n\t"
        "s_add_u32 s30, s29, 128\n\t"
        "s_load_dwordx16 s[64:79], %[cb], s30\n\t"
        "s_add_u32 s30, s29, 192\n\t"
        "s_load_dwordx16 s[80:95], %[cb], s30\n\t"
        "s_lshr_b32 s31, s29, 6\n\t"
        "s_load_dword s28, %[c2], s31\n\t"
        "s_add_u32 s29, s29, 256\n\t"
        "s_waitcnt lgkmcnt(0)\n\t"
        // ---- approx cross: 64 fma, 4 chains, d ascending ----
        "v_mul_f32 v81, s32, v16\n\t"
        "v_mul_f32 v82, s33, v17\n\t"
        "v_mul_f32 v83, s34, v18\n\t"
        "v_mul_f32 v84, s35, v19\n\t"
        FQ("36","37","38","39","20","21","22","23")
        FQ("40","41","42","43","24","25","26","27")
        FQ("44","45","46","47","28","29","30","31")
        FQ("48","49","50","51","32","33","34","35")
        FQ("52","53","54","55","36","37","38","39")
        FQ("56","57","58","59","40","41","42","43")
        FQ("60","61","62","63","44","45","46","47")
        FQ("64","65","66","67","48","49","50","51")
        FQ("68","69","70","71","52","53","54","55")
        FQ("72","73","74","75","56","57","58","59")
        FQ("76","77","78","79","60","61","62","63")
        FQ("80","81","82","83","64","65","66","67")
        FQ("84","85","86","87","68","69","70","71")
        FQ("88","89","90","91","72","73","74","75")
        FQ("92","93","94","95","76","77","78","79")
        // ---- d2a, min, candidate bit ----
        "v_add_f32 v96, v81, v82\n\t"
        "v_add_f32 v97, v83, v84\n\t"
        "v_add_f32 v96, v96, v97\n\t"          // crossA
        "v_fma_f32 v96, v96, -2.0, v80\n\t"    // -2*crossA + r2
        "v_add_f32 v96, s28, v96\n\t"          // d2a
        "v_add_f32 v97, %[mg], v85\n\t"        // thr = bestA + margin
        "v_cmp_lt_f32 vcc, v96, v97\n\t"
        "v_cndmask_b32 v97, 0, v86, vcc\n\t"   // bit or 0
        "v_or_b32 v87, v87, v97\n\t"
        "v_min_f32 v85, v85, v96\n\t"
        "v_lshlrev_b32 v86, 1, v86\n\t"
        "s_sub_u32 s24, s24, 1\n\t"
        "s_cmp_lg_u32 s24, 0\n\t"
        "s_cbranch_scc1 Linn_%=\n\t"
        // ---- rotate mask stores: v88<-v89<-...<-v95<-v87 ----
        "v_mov_b32 v88, v89\n\t"
        "v_mov_b32 v89, v90\n\t"
        "v_mov_b32 v90, v91\n\t"
        "v_mov_b32 v91, v92\n\t"
        "v_mov_b32 v92, v93\n\t"
        "v_mov_b32 v93, v94\n\t"
        "v_mov_b32 v94, v95\n\t"
        "v_mov_b32 v95, v87\n\t"
        "v_mov_b32 v87, 0\n\t"
        "v_mov_b32 v86, 1\n\t"
        "s_sub_u32 s25, s25, 1\n\t"
        "s_cmp_lg_u32 s25, 0\n\t"
        "s_cbranch_scc1 Lout_%=\n\t"
        "v_mov_b32 %[o0], v88\n\t"
        "v_mov_b32 %[o1], v89\n\t"
        "v_mov_b32 %[o2], v90\n\t"
        "v_mov_b32 %[o3], v91\n\t"
        "v_mov_b32 %[o4], v92\n\t"
        "v_mov_b32 %[o5], v93\n\t"
        "v_mov_b32 %[o6], v94\n\t"
        "v_mov_b32 %[o7], v95\n\t"
        : [o0] "=v"(mk0), [o1] "=v"(mk1), [o2] "=v"(mk2), [o3] "=v"(mk3),
          [o4] "=v"(mk4), [o5] "=v"(mk5), [o6] "=v"(mk6), [o7] "=v"(mk7)
        : [ra] "v"(ra), [cb] "s"(cbw), [c2] "s"(c2w), [mg] "s"(2.0e-4f)
        : "vcc", "scc",
          "v16","v17","v18","v19","v20","v21","v22","v23","v24","v25","v26","v27",
          "v28","v29","v30","v31","v32","v33","v34","v35","v36","v37","v38","v39",
          "v40","v41","v42","v43","v44","v45","v46","v47","v48","v49","v50","v51",
          "v52","v53","v54","v55","v56","v57","v58","v59","v60","v61","v62","v63",
          "v64","v65","v66","v67","v68","v69","v70","v71","v72","v73","v74","v75",
          "v76","v77","v78","v79","v80","v81","v82","v83","v84","v85","v86","v87",
          "v88","v89","v90","v91","v92","v93","v94","v95","v96","v97",
          "s24","s25","s28","s29","s30","s31",
          "s32","s33","s34","s35","s36","s37","s38","s39",
          "s40","s41","s42","s43","s44","s45","s46","s47","s48","s49","s50","s51",
          "s52","s53","s54","s55","s56","s57","s58","s59","s60","s61","s62","s63",
          "s64","s65","s66","s67","s68","s69","s70","s71","s72","s73","s74","s75",
          "s76","s77","s78","s79","s80","s81","s82","s83","s84","s85","s86","s87",
          "s88","s89","s90","s91","s92","s93","s94","s95");

    // ---- pass 2 (cold): exact recompute for candidates, ascending m ----
    const unsigned mk[8] = {mk0, mk1, mk2, mk3, mk4, mk5, mk6, mk7};
    const float* rr = res_in + (size_t)point * DD;
    // exact r2 (same pairwise sequence as asm; IEEE-deterministic)
    float rv[DD];
#pragma unroll
    for (int i = 0; i < DD / 4; ++i) {
        float4 v = ((const float4*)rr)[i];
        rv[4 * i] = v.x; rv[4 * i + 1] = v.y; rv[4 * i + 2] = v.z; rv[4 * i + 3] = v.w;
    }
    float r8[8];
#pragma unroll
    for (int j = 0; j < 8; ++j) r8[j] = rv[j] * rv[j];
#pragma unroll
    for (int i = 8; i < DD; i += 8) {
#pragma unroll
        for (int j = 0; j < 8; ++j) { float t = rv[i + j] * rv[i + j]; r8[j] += t; }
    }
    const float r2e = ((r8[0] + r8[1]) + (r8[2] + r8[3])) + ((r8[4] + r8[5]) + (r8[6] + r8[7]));

    float beste = __builtin_inff();
    int bide = m0;
    for (int g = 0; g < 8; ++g) {
        unsigned mask = mk[g];
        while (mask) {
            const int bit = __builtin_ctz(mask);
            mask &= mask - 1;
            const int m = m0 + g * 32 + bit;
            const float4* crow4 = (const float4*)(cbk + (size_t)m * DD);
            float ch[4] = {0.0f, 0.0f, 0.0f, 0.0f};
            // exact SSE order: blocks ascending, groups {12,8,4,0}+b
#pragma unroll
            for (int b = 0; b < DD; b += 16) {
                float cw[16], rw[16];
#pragma unroll
                for (int q = 0; q < 4; ++q) {
                    float4 cv = crow4[(b >> 2) + q];
                    cw[4 * q] = cv.x; cw[4 * q + 1] = cv.y; cw[4 * q + 2] = cv.z; cw[4 * q + 3] = cv.w;
                    rw[4 * q] = rv[b + 4 * q]; rw[4 * q + 1] = rv[b + 4 * q + 1];
                    rw[4 * q + 2] = rv[b + 4 * q + 2]; rw[4 * q + 3] = rv[b + 4 * q + 3];
                }
#pragma unroll
                for (int gg = 3; gg >= 0; --gg) {
#pragma unroll
                    for (int j = 0; j < 4; ++j) {
                        const int d = gg * 4 + j;
                        float tp = rw[d] * cw[d];
                        ch[j] += tp;
                    }
                }
            }
            const float cross = (ch[0] + ch[1]) + (ch[2] + ch[3]);
            const float tt = __builtin_fmaf(-2.0f, cross, r2e);
            const float d2 = tt + c2k[m];
            if (d2 < beste) { beste = d2; bide = m; }  // ascending m + strict <
        }
    }

    // --- combine across the 8 m-chunks (waves), first-occurrence semantics ---
    __shared__ float sb[WPB * 64];
    __shared__ int   si[WPB * 64];
    __shared__ int   fidx[64];
    sb[wv * 64 + lane] = beste;
    si[wv * 64 + lane] = bide;
    __syncthreads();
    if (tid < 64) {
        float b = sb[lane];
        int ix = si[lane];
#pragma unroll
        for (int w = 1; w < WPB; ++w) {
            float ob = sb[w * 64 + lane];
            int oi = si[w * 64 + lane];
            if (ob < b) { b = ob; ix = oi; }  // strict <: smaller-m chunk wins ties
        }
        fidx[lane] = ix;
        idx_out[point] = (float)ix;  // exact for ix < 2^24
    }
    __syncthreads();

    // --- residual update: 512 threads x 8 elems, coalesced ---
    const size_t base = (size_t)blockIdx.x * 64 * DD;
#pragma unroll
    for (int i = 0; i < 8; ++i) {
        const int e = i * 512 + tid;
        const int p = e >> 6;
        const int d = e & 63;
        const int ix = fidx[p];
        res_out[base + e] = res_in[base + e] - cbk[(size_t)ix * DD + d];  // exact fp32 sub
    }
}

// ---- finalize: quantized = x - residual ----
__global__ __launch_bounds__(256) void rvq_final(const float* __restrict__ x,
                                                 const float* __restrict__ res,
                                                 float* __restrict__ q) {
#pragma clang fp contract(off)
    int i = blockIdx.x * 256 + threadIdx.x;
    q[i] = x[i] - res[i];
}

extern "C" void kernel_launch(void* const* d_in, const int* in_sizes, int n_in,
                              void* d_out, int out_size, void* d_ws, size_t ws_size,
                              hipStream_t stream) {
    const float* x  = (const float*)d_in[0];
    const float* cb = (const float*)d_in[1];

    float* out = (float*)d_out;
    float* quant = out;                 // QSIZE floats
    float* idx_out = out + QSIZE;       // K*NPTS floats (indices as float)

    float* c2   = (float*)d_ws;                       // K*M floats (64 KB)
    float* res1 = c2 + (size_t)KK * MM;               // NPTS*D floats (8 MB)
    float* R[2] = { quant, res1 };                    // ping-pong residual

    rvq_prep<<<(KK * MM) / 256, 256, 0, stream>>>(cb, c2);

    for (int k = 0; k < KK; ++k) {
        const float* rin = (k == 0) ? x : R[(k - 1) & 1];
        float* rout = R[k & 1];
        rvq_step<<<NPTS / 64, 512, 0, stream>>>(
            rin, rout,
            cb + (size_t)k * MM * DD,
            c2 + (size_t)k * MM,
            idx_out + (size_t)k * NPTS);
    }

    rvq_final<<<QSIZE / 256, 256, 0, stream>>>(x, R[(KK - 1) & 1], quant);
}

// Round 7
// 1547.043 us; speedup vs baseline: 1.0046x; 1.0046x over previous
//
#include <hip/hip_runtime.h>

// Residual VQ, bit-exact vs numpy. B=16 S=2048 D=64 K=8 M=2048.
//
// Numerics contract (verified bit-exact R1-R6, absmax 0.0):
//  - r2/c2: numpy pairwise_sum 8-accumulator order, no FMA contraction
//  - cross: numpy einsum SSE order: 4 chains (d mod 4), per 16-block groups
//           {12,8,4,0}+j, blocks ascending, chains init by first product,
//           hsum (L0+L1)+(L2+L3)
//  - t = fl(r2 - 2*cross) via fma(-2,cross,r2); d2 = fl(t + c2) (add commutes)
//  - argmin: first occurrence (strict <; groups/bits ascending; combine
//    ascending chunks)
//
// R7: two-phase, both phases in ONE asm block (R6's C++ pass-2 spilled rv[]
// to scratch: WRITE_SIZE 8.3->26.7 MB/step, the regression). Pass 1: exact
// r2 + approximate fma cross (1 inst/elem) + running-min + candidate bitmask,
// margin 1e-4 (rigorous |d2a-d2e| <= ~1.6e-5: fma-vs-SSE cross delta ~2.4e-7
// + 2 ulp(64) rounding divergence; running-best filter is a superset of
// final-best filter so the true argmin bit is always set). Pass 2: per mask
// group, while-any-lane loop: v_ffbl_b32 lowest bit (ascending m), gather
// codebook row in 16-float quarters (quarter == SSE 16-block), exact
// mul/add chain recompute with residual STILL pinned in v16-v79; inactive
// lanes suppressed via saved active mask in s[22:23].

#define BB 16
#define SS 2048
#define DD 64
#define KK 8
#define MM 2048
#define NPTS (BB * SS)      // 32768
#define QSIZE (NPTS * DD)   // 2097152
#define WPB 8               // waves per block
#define MCHUNK (MM / WPB)   // 256 m per wave

// ---- prep: c2[k][m] (numpy pairwise) ----
__global__ __launch_bounds__(256) void rvq_prep(const float* __restrict__ cb,
                                                float* __restrict__ c2) {
#pragma clang fp contract(off)
    int tid = blockIdx.x * 256 + threadIdx.x;  // 0 .. K*M-1
    const float* row = cb + (size_t)tid * DD;
    float r[8];
#pragma unroll
    for (int j = 0; j < 8; ++j) { float v = row[j]; r[j] = v * v; }
#pragma unroll
    for (int i = 8; i < DD; i += 8) {
#pragma unroll
        for (int j = 0; j < 8; ++j) { float v = row[i + j]; float t = v * v; r[j] += t; }
    }
    c2[tid] = ((r[0] + r[1]) + (r[2] + r[3])) + ((r[4] + r[5]) + (r[6] + r[7]));
}

// r2 group: 8 squares (mul then add, separate roundings) into accs v80..v87
#define R2G(a0,a1,a2,a3,a4,a5,a6,a7) \
    "v_mul_f32 v96, v" a0 ", v" a0 "\n\tv_add_f32 v80, v80, v96\n\t" \
    "v_mul_f32 v96, v" a1 ", v" a1 "\n\tv_add_f32 v81, v81, v96\n\t" \
    "v_mul_f32 v96, v" a2 ", v" a2 "\n\tv_add_f32 v82, v82, v96\n\t" \
    "v_mul_f32 v96, v" a3 ", v" a3 "\n\tv_add_f32 v83, v83, v96\n\t" \
    "v_mul_f32 v96, v" a4 ", v" a4 "\n\tv_add_f32 v84, v84, v96\n\t" \
    "v_mul_f32 v96, v" a5 ", v" a5 "\n\tv_add_f32 v85, v85, v96\n\t" \
    "v_mul_f32 v96, v" a6 ", v" a6 "\n\tv_add_f32 v86, v86, v96\n\t" \
    "v_mul_f32 v96, v" a7 ", v" a7 "\n\tv_add_f32 v87, v87, v96\n\t"

// pass-1 fma quad: 4 interleaved chains v81..v84, d ascending (approx order free)
#define FQ(s0,s1,s2,s3,w0,w1,w2,w3) \
    "v_fma_f32 v81, s" s0 ", v" w0 ", v81\n\t" \
    "v_fma_f32 v82, s" s1 ", v" w1 ", v82\n\t" \
    "v_fma_f32 v83, s" s2 ", v" w2 ", v83\n\t" \
    "v_fma_f32 v84, s" s3 ", v" w3 ", v84\n\t"

// pass-2 exact chain ops: mul-then-add (c reg, r reg, chain reg), and init
#define XA(c, r, ch) \
    "v_mul_f32 v116, v" c ", v" r "\n\tv_add_f32 v" ch ", v" ch ", v116\n\t"
#define XI(c, r, ch) \
    "v_mul_f32 v" ch ", v" c ", v" r "\n\t"

// pass-2: one 16-float quarter Q (==SSE block) of candidate row; QOFFI = Q*64
// byte literal add (skipped for Q0). groups gg=3,2,1,0; c=v(98+gg*4+j),
// r=v(16+Q*16+gg*4+j), chain=v(81+j). INIT3 only for Q0/gg=3.
#define QADDR(QOFFADD) \
    "v_lshlrev_b32 v97, 8, v96\n\t" \
    QOFFADD \
    "v_mov_b32 v115, %[cbh]\n\t" \
    "v_add_co_u32 v114, vcc, %[cbl], v97\n\t" \
    "v_addc_co_u32 v115, vcc, 0, v115, vcc\n\t" \
    "global_load_dwordx4 v[98:101], v[114:115], off\n\t" \
    "global_load_dwordx4 v[102:105], v[114:115], off offset:16\n\t" \
    "global_load_dwordx4 v[106:109], v[114:115], off offset:32\n\t" \
    "global_load_dwordx4 v[110:113], v[114:115], off offset:48\n\t" \
    "s_waitcnt vmcnt(0)\n\t"

// consume quarter: gg 3..0, j 0..3. r-base = 16+Q*16.
#define QCONS(r12,r13,r14,r15, r8,r9,r10,r11, r4,r5,r6,r7, r0,r1,r2,r3, G3A) \
    G3A("110", r12, "81") G3A("111", r13, "82") G3A("112", r14, "83") G3A("113", r15, "84") \
    XA("106", r8,  "81") XA("107", r9,  "82") XA("108", r10, "83") XA("109", r11, "84") \
    XA("102", r4,  "81") XA("103", r5,  "82") XA("104", r6,  "83") XA("105", r7,  "84") \
    XA("98",  r0,  "81") XA("99",  r1,  "82") XA("100", r2,  "83") XA("101", r3,  "84")

// pass-2 group G (mask reg MR, m-base literal OR): while-any loop
#define PASS2G(G, MR, ORBIT) \
    "Lh" G "_%=:\n\t" \
    "v_cmp_ne_u32 vcc, 0, v" MR "\n\t" \
    "s_cbranch_vccz Le" G "_%=\n\t" \
    "s_mov_b64 s[22:23], vcc\n\t" \
    "v_ffbl_b32 v96, v" MR "\n\t" \
    "v_and_b32 v96, 31, v96\n\t" \
    "v_add_u32 v97, -1, v" MR "\n\t" \
    "v_and_b32 v" MR ", v" MR ", v97\n\t" \
    ORBIT \
    /* quarter 0 (init chains), 1, 2, 3 */ \
    QADDR("") \
    QCONS("28","29","30","31","24","25","26","27","20","21","22","23","16","17","18","19", XI) \
    QADDR("v_add_u32 v97, 64, v97\n\t") \
    QCONS("44","45","46","47","40","41","42","43","36","37","38","39","32","33","34","35", XA) \
    QADDR("v_add_u32 v97, 0x80, v97\n\t") \
    QCONS("60","61","62","63","56","57","58","59","52","53","54","55","48","49","50","51", XA) \
    QADDR("v_add_u32 v97, 0xc0, v97\n\t") \
    QCONS("76","77","78","79","72","73","74","75","68","69","70","71","64","65","66","67", XA) \
    /* hsum + d2 exact */ \
    "v_add_f32 v97, v81, v82\n\t" \
    "v_add_f32 v116, v83, v84\n\t" \
    "v_add_f32 v97, v97, v116\n\t" \
    "v_fma_f32 v97, v97, -2.0, v80\n\t" \
    "v_lshlrev_b32 v114, 2, v96\n\t" \
    "v_mov_b32 v115, %[c2h]\n\t" \
    "v_add_co_u32 v114, vcc, %[c2l], v114\n\t" \
    "v_addc_co_u32 v115, vcc, 0, v115, vcc\n\t" \
    "global_load_dword v116, v[114:115], off\n\t" \
    "s_waitcnt vmcnt(0)\n\t" \
    "v_add_f32 v97, v116, v97\n\t" \
    /* masked update: strict <, active lanes only */ \
    "v_cmp_lt_f32 vcc, v97, v85\n\t" \
    "s_and_b64 vcc, vcc, s[22:23]\n\t" \
    "v_cndmask_b32 v85, v85, v97, vcc\n\t" \
    "v_add_u32 v116, %[m0], v96\n\t" \
    "v_cndmask_b32 v86, v86, v116, vcc\n\t" \
    "s_branch Lh" G "_%=\n\t" \
    "Le" G "_%=:\n\t"

// ---- one RVQ step ----
// grid = NPTS/64 = 512 blocks x 512 threads (8 waves).
// lane = point; wave = 256-m chunk.
__global__ __launch_bounds__(512, 4) void rvq_step(const float* __restrict__ res_in,
                                                   float* __restrict__ res_out,
                                                   const float* __restrict__ cbk,  // (M,D)
                                                   const float* __restrict__ c2k,  // (M,)
                                                   float* __restrict__ idx_out) {  // (NPTS,)
#pragma clang fp contract(off)
    const int tid = threadIdx.x;
    const int lane = tid & 63;
    const int wv = __builtin_amdgcn_readfirstlane(tid >> 6);  // wave-uniform
    const int point = blockIdx.x * 64 + lane;
    const int m0 = wv * MCHUNK;
    const float* cbw = cbk + (size_t)m0 * DD;
    const float* c2w = c2k + m0;
    const unsigned long long ra = (unsigned long long)(res_in + (size_t)point * DD);
    const unsigned cbl = (unsigned)(unsigned long long)cbw;
    const unsigned cbh = (unsigned)(((unsigned long long)cbw) >> 32);
    const unsigned c2l = (unsigned)(unsigned long long)c2w;
    const unsigned c2h = (unsigned)(((unsigned long long)c2w) >> 32);

    float best;
    int bidx;
    asm volatile(
        // ---- residual: 64 floats -> v[16:79] ----
        "global_load_dwordx4 v[16:19], %[ra], off\n\t"
        "global_load_dwordx4 v[20:23], %[ra], off offset:16\n\t"
        "global_load_dwordx4 v[24:27], %[ra], off offset:32\n\t"
        "global_load_dwordx4 v[28:31], %[ra], off offset:48\n\t"
        "global_load_dwordx4 v[32:35], %[ra], off offset:64\n\t"
        "global_load_dwordx4 v[36:39], %[ra], off offset:80\n\t"
        "global_load_dwordx4 v[40:43], %[ra], off offset:96\n\t"
        "global_load_dwordx4 v[44:47], %[ra], off offset:112\n\t"
        "global_load_dwordx4 v[48:51], %[ra], off offset:128\n\t"
        "global_load_dwordx4 v[52:55], %[ra], off offset:144\n\t"
        "global_load_dwordx4 v[56:59], %[ra], off offset:160\n\t"
        "global_load_dwordx4 v[60:63], %[ra], off offset:176\n\t"
        "global_load_dwordx4 v[64:67], %[ra], off offset:192\n\t"
        "global_load_dwordx4 v[68:71], %[ra], off offset:208\n\t"
        "global_load_dwordx4 v[72:75], %[ra], off offset:224\n\t"
        "global_load_dwordx4 v[76:79], %[ra], off offset:240\n\t"
        "s_waitcnt vmcnt(0)\n\t"
        // ---- exact r2, numpy pairwise 8-acc order (accs v80..v87) ----
        "v_mul_f32 v80, v16, v16\n\t"
        "v_mul_f32 v81, v17, v17\n\t"
        "v_mul_f32 v82, v18, v18\n\t"
        "v_mul_f32 v83, v19, v19\n\t"
        "v_mul_f32 v84, v20, v20\n\t"
        "v_mul_f32 v85, v21, v21\n\t"
        "v_mul_f32 v86, v22, v22\n\t"
        "v_mul_f32 v87, v23, v23\n\t"
        R2G("24","25","26","27","28","29","30","31")
        R2G("32","33","34","35","36","37","38","39")
        R2G("40","41","42","43","44","45","46","47")
        R2G("48","49","50","51","52","53","54","55")
        R2G("56","57","58","59","60","61","62","63")
        R2G("64","65","66","67","68","69","70","71")
        R2G("72","73","74","75","76","77","78","79")
        "v_add_f32 v96, v80, v81\n\t"
        "v_add_f32 v97, v82, v83\n\t"
        "v_add_f32 v96, v96, v97\n\t"
        "v_add_f32 v97, v84, v85\n\t"
        "v_add_f32 v80, v86, v87\n\t"
        "v_add_f32 v97, v97, v80\n\t"
        "v_add_f32 v80, v96, v97\n\t"      // r2 exact -> v80
        // ---- pass 1 init: bestA v85, bit v86, cur-mask v87, stores v88-95 ----
        "v_mov_b32 v85, 0x7f800000\n\t"
        "v_mov_b32 v86, 1\n\t"
        "v_mov_b32 v87, 0\n\t"
        "v_mov_b32 v88, 0\n\t"
        "v_mov_b32 v89, 0\n\t"
        "v_mov_b32 v90, 0\n\t"
        "v_mov_b32 v91, 0\n\t"
        "v_mov_b32 v92, 0\n\t"
        "v_mov_b32 v93, 0\n\t"
        "v_mov_b32 v94, 0\n\t"
        "v_mov_b32 v95, 0\n\t"
        "s_mov_b32 s29, 0\n\t"             // byte offset into chunk
        "s_mov_b32 s25, 8\n\t"             // outer (8 groups of 32 m)
        "Lout_%=:\n\t"
        "s_mov_b32 s24, 32\n\t"            // inner
        "Linn_%=:\n\t"
        // ---- row m -> s[32:95]; c2m -> s28 ----
        "s_load_dwordx16 s[32:47], %[cb], s29\n\t"
        "s_add_u32 s30, s29, 64\n\t"
        "s_load_dwordx16 s[48:63], %[cb], s30\n\t"
        "s_add_u32 s30, s29, 128\n\t"
        "s_load_dwordx16 s[64:79], %[cb], s30\n\t"
        "s_add_u32 s30, s29, 192\n\t"
        "s_load_dwordx16 s[80:95], %[cb], s30\n\t"
        "s_lshr_b32 s31, s29, 6\n\t"
        "s_load_dword s28, %[c2], s31\n\t"
        "s_add_u32 s29, s29, 256\n\t"
        "s_waitcnt lgkmcnt(0)\n\t"
        // ---- approx cross: 64 fma, 4 chains, d ascending ----
        "v_mul_f32 v81, s32, v16\n\t"
        "v_mul_f32 v82, s33, v17\n\t"
        "v_mul_f32 v83, s34, v18\n\t"
        "v_mul_f32 v84, s35, v19\n\t"
        FQ("36","37","38","39","20","21","22","23")
        FQ("40","41","42","43","24","25","26","27")
        FQ("44","45","46","47","28","29","30","31")
        FQ("48","49","50","51","32","33","34","35")
        FQ("52","53","54","55","36","37","38","39")
        FQ("56","57","58","59","40","41","42","43")
        FQ("60","61","62","63","44","45","46","47")
        FQ("64","65","66","67","48","49","50","51")
        FQ("68","69","70","71","52","53","54","55")
        FQ("72","73","74","75","56","57","58","59")
        FQ("76","77","78","79","60","61","62","63")
        FQ("80","81","82","83","64","65","66","67")
        FQ("84","85","86","87","68","69","70","71")
        FQ("88","89","90","91","72","73","74","75")
        FQ("92","93","94","95","76","77","78","79")
        // ---- d2a, running min, candidate bit ----
        "v_add_f32 v96, v81, v82\n\t"
        "v_add_f32 v97, v83, v84\n\t"
        "v_add_f32 v96, v96, v97\n\t"          // crossA
        "v_fma_f32 v96, v96, -2.0, v80\n\t"    // -2*crossA + r2e (same seq as exact)
        "v_add_f32 v96, s28, v96\n\t"          // d2a
        "v_add_f32 v97, %[mg], v85\n\t"        // thr = bestA + margin
        "v_cmp_lt_f32 vcc, v96, v97\n\t"
        "v_cndmask_b32 v97, 0, v86, vcc\n\t"
        "v_or_b32 v87, v87, v97\n\t"
        "v_min_f32 v85, v85, v96\n\t"
        "v_lshlrev_b32 v86, 1, v86\n\t"
        "s_sub_u32 s24, s24, 1\n\t"
        "s_cmp_lg_u32 s24, 0\n\t"
        "s_cbranch_scc1 Linn_%=\n\t"
        // ---- rotate mask stores: v88<-v89<-...<-v95<-v87 ----
        "v_mov_b32 v88, v89\n\t"
        "v_mov_b32 v89, v90\n\t"
        "v_mov_b32 v90, v91\n\t"
        "v_mov_b32 v91, v92\n\t"
        "v_mov_b32 v92, v93\n\t"
        "v_mov_b32 v93, v94\n\t"
        "v_mov_b32 v94, v95\n\t"
        "v_mov_b32 v95, v87\n\t"
        "v_mov_b32 v87, 0\n\t"
        "v_mov_b32 v86, 1\n\t"
        "s_sub_u32 s25, s25, 1\n\t"
        "s_cmp_lg_u32 s25, 0\n\t"
        "s_cbranch_scc1 Lout_%=\n\t"
        // ==== pass 2: exact recompute for candidates (rv still in v16-79) ====
        "v_mov_b32 v85, 0x7f800000\n\t"        // bestE
        "v_mov_b32 v86, 0\n\t"                 // bidxE
        PASS2G("0", "88", "")
        PASS2G("1", "89", "v_or_b32 v96, 32, v96\n\t")
        PASS2G("2", "90", "v_or_b32 v96, 64, v96\n\t")
        PASS2G("3", "91", "v_or_b32 v96, 0x60, v96\n\t")
        PASS2G("4", "92", "v_or_b32 v96, 0x80, v96\n\t")
        PASS2G("5", "93", "v_or_b32 v96, 0xa0, v96\n\t")
        PASS2G("6", "94", "v_or_b32 v96, 0xc0, v96\n\t")
        PASS2G("7", "95", "v_or_b32 v96, 0xe0, v96\n\t")
        "v_mov_b32 %[ob], v85\n\t"
        "v_mov_b32 %[oi], v86\n\t"
        : [ob] "=v"(best), [oi] "=v"(bidx)
        : [ra] "v"(ra), [cb] "s"(cbw), [c2] "s"(c2w), [m0] "s"(m0),
          [mg] "s"(1.0e-4f), [cbl] "s"(cbl), [cbh] "s"(cbh),
          [c2l] "s"(c2l), [c2h] "s"(c2h)
        : "vcc", "scc",
          "v16","v17","v18","v19","v20","v21","v22","v23","v24","v25","v26","v27",
          "v28","v29","v30","v31","v32","v33","v34","v35","v36","v37","v38","v39",
          "v40","v41","v42","v43","v44","v45","v46","v47","v48","v49","v50","v51",
          "v52","v53","v54","v55","v56","v57","v58","v59","v60","v61","v62","v63",
          "v64","v65","v66","v67","v68","v69","v70","v71","v72","v73","v74","v75",
          "v76","v77","v78","v79","v80","v81","v82","v83","v84","v85","v86","v87",
          "v88","v89","v90","v91","v92","v93","v94","v95","v96","v97","v98","v99",
          "v100","v101","v102","v103","v104","v105","v106","v107","v108","v109",
          "v110","v111","v112","v113","v114","v115","v116",
          "s22","s23","s24","s25","s28","s29","s30","s31",
          "s32","s33","s34","s35","s36","s37","s38","s39",
          "s40","s41","s42","s43","s44","s45","s46","s47","s48","s49","s50","s51",
          "s52","s53","s54","s55","s56","s57","s58","s59","s60","s61","s62","s63",
          "s64","s65","s66","s67","s68","s69","s70","s71","s72","s73","s74","s75",
          "s76","s77","s78","s79","s80","s81","s82","s83","s84","s85","s86","s87",
          "s88","s89","s90","s91","s92","s93","s94","s95");

    // --- combine across the 8 m-chunks (waves), first-occurrence semantics ---
    __shared__ float sb[WPB * 64];
    __shared__ int   si[WPB * 64];
    __shared__ int   fidx[64];
    sb[wv * 64 + lane] = best;
    si[wv * 64 + lane] = bidx;
    __syncthreads();
    if (tid < 64) {
        float b = sb[lane];
        int ix = si[lane];
#pragma unroll
        for (int w = 1; w < WPB; ++w) {
            float ob = sb[w * 64 + lane];
            int oi = si[w * 64 + lane];
            if (ob < b) { b = ob; ix = oi; }  // strict <: smaller-m chunk wins ties
        }
        fidx[lane] = ix;
        idx_out[point] = (float)ix;  // exact for ix < 2^24
    }
    __syncthreads();

    // --- residual update: 512 threads x 8 elems, coalesced ---
    const size_t base = (size_t)blockIdx.x * 64 * DD;
#pragma unroll
    for (int i = 0; i < 8; ++i) {
        const int e = i * 512 + tid;
        const int p = e >> 6;
        const int d = e & 63;
        const int ix = fidx[p];
        res_out[base + e] = res_in[base + e] - cbk[(size_t)ix * DD + d];  // exact fp32 sub
    }
}

// ---- finalize: quantized = x - residual ----
__global__ __launch_bounds__(256) void rvq_final(const float* __restrict__ x,
                                                 const float* __restrict__ res,
                                                 float* __restrict__ q) {
#pragma clang fp contract(off)
    int i = blockIdx.x * 256 + threadIdx.x;
    q[i] = x[i] - res[i];
}

extern "C" void kernel_launch(void* const* d_in, const int* in_sizes, int n_in,
                              void* d_out, int out_size, void* d_ws, size_t ws_size,
                              hipStream_t stream) {
    const float* x  = (const float*)d_in[0];
    const float* cb = (const float*)d_in[1];

    float* out = (float*)d_out;
    float* quant = out;                 // QSIZE floats
    float* idx_out = out + QSIZE;       // K*NPTS floats (indices as float)

    float* c2   = (float*)d_ws;                       // K*M floats (64 KB)
    float* res1 = c2 + (size_t)KK * MM;               // NPTS*D floats (8 MB)
    float* R[2] = { quant, res1 };                    // ping-pong residual

    rvq_prep<<<(KK * MM) / 256, 256, 0, stream>>>(cb, c2);

    for (int k = 0; k < KK; ++k) {
        const float* rin = (k == 0) ? x : R[(k - 1) & 1];
        float* rout = R[k & 1];
        rvq_step<<<NPTS / 64, 512, 0, stream>>>(
            rin, rout,
            cb + (size_t)k * MM * DD,
            c2 + (size_t)k * MM,
            idx_out + (size_t)k * NPTS);
    }

    rvq_final<<<QSIZE / 256, 256, 0, stream>>>(x, R[(KK - 1) & 1], quant);
}